// Round 15
// baseline (94.222 us; speedup 1.0000x reference)
//
#include <hip/hip_runtime.h>
#include <hip/hip_bf16.h>

// SelfAttention: N=2, S=2048, E=1024, H=16, D=64.
// Round 15: counted-vmcnt 3-buffer attn pipeline (T3/T4). KVBLK=32, 3 LDS
// buffers per split (48KB total) -> raw s_barrier + s_waitcnt vmcnt(2)
// (never 0 mid-loop; tile t+1 loads stay in flight across the barrier), and
// 3 blocks/CU (24 waves) with independent barrier domains. Softmax recipe =
// round 10 (pre-scaled Q, ones-MFMA rowsum, sign-AND mask, cvt_pk+permlane).
// prep / out_proj = round 14.

#define S_LEN  2048
#define EMB    1024
#define NHEAD  16
#define DHEAD  64
#define NBATCH 2

// log2(e)/32: folded into Q so QK^T lands pre-scaled for exp2
#define KSC 0.04508422002778011f

typedef float              f32x4    __attribute__((ext_vector_type(4)));
typedef float              f32x16   __attribute__((ext_vector_type(16)));
typedef __bf16             bf16x8   __attribute__((ext_vector_type(8)));
typedef unsigned short     ushort8v __attribute__((ext_vector_type(8)));
typedef unsigned long long u64;

union FragU { ushort8v u; bf16x8 b; };
union BFrag { unsigned u32[4]; bf16x8 b; };

__device__ __forceinline__ unsigned short f2b(float f) {
  union { __hip_bfloat16 h; unsigned short u; } c;
  c.h = __float2bfloat16(f);
  return c.u;
}

__device__ __forceinline__ unsigned int cvt_pk_bf16(float lo, float hi) {
  unsigned int r;
  asm("v_cvt_pk_bf16_f32 %0, %1, %2" : "=v"(r) : "v"(lo), "v"(hi));
  return r;
}

#define PSWAP(a, b) asm("v_permlane32_swap_b32 %0, %1" : "+v"(a), "+v"(b))

#define GLD16(g, l)                                                            \
  __builtin_amdgcn_global_load_lds(                                            \
      (__attribute__((address_space(1))) void*)(g),                            \
      (__attribute__((address_space(3))) void*)(l), 16, 0, 0)

#define WAITVM_(N) asm volatile("s_waitcnt vmcnt(" #N ")" ::: "memory")
#define WAITVM(N)  WAITVM_(N)

// ------------------------------------------------------- fused prep kernel
__global__ __launch_bounds__(256) void prep(
    const float* __restrict__ Wo, unsigned short* __restrict__ Wb,
    const float* __restrict__ Kg, unsigned short* __restrict__ Kb,
    const float* __restrict__ Vg, unsigned short* __restrict__ Vt,
    const int* __restrict__ Mg,   u64* __restrict__ Mb)
{
  const int bid = blockIdx.x;
  const int tid = threadIdx.x;
  if (bid < 2560) {
    const float* X = (bid < 512) ? Wo : Kg;
    unsigned short* Y = (bid < 512) ? Wb : Kb;
    const int bb = (bid < 512) ? bid : bid - 512;
    const size_t i = ((size_t)bb * 256 + tid) * 8;
    float4 a = *reinterpret_cast<const float4*>(X + i);
    float4 b = *reinterpret_cast<const float4*>(X + i + 4);
    ushort8v u;
    u[0] = f2b(a.x); u[1] = f2b(a.y); u[2] = f2b(a.z); u[3] = f2b(a.w);
    u[4] = f2b(b.x); u[5] = f2b(b.y); u[6] = f2b(b.z); u[7] = f2b(b.w);
    *reinterpret_cast<ushort8v*>(Y + i) = u;
  } else if (bid < 3584) {
    __shared__ unsigned short T[64][72];
    const int b2 = bid - 2560;
    const int sb = b2 & 31, h = (b2 >> 5) & 15, n = b2 >> 9;
    const int r = tid >> 2, cb = (tid & 3) * 16;
    const float* src = Vg + ((size_t)(n * S_LEN + sb * 64 + r)) * EMB + h * DHEAD + cb;
    ushort8v u0, u1;
#pragma unroll
    for (int j = 0; j < 2; ++j) {
      float4 x = *reinterpret_cast<const float4*>(src + j * 4);
      u0[j*4+0] = f2b(x.x); u0[j*4+1] = f2b(x.y); u0[j*4+2] = f2b(x.z); u0[j*4+3] = f2b(x.w);
      float4 y = *reinterpret_cast<const float4*>(src + 8 + j * 4);
      u1[j*4+0] = f2b(y.x); u1[j*4+1] = f2b(y.y); u1[j*4+2] = f2b(y.z); u1[j*4+3] = f2b(y.w);
    }
    *reinterpret_cast<ushort8v*>(&T[r][cb])     = u0;
    *reinterpret_cast<ushort8v*>(&T[r][cb + 8]) = u1;
    __syncthreads();
    const int d = tid >> 2, sc_ = (tid & 3) * 16;
    ushort8v o0, o1;
#pragma unroll
    for (int j = 0; j < 8; ++j) { o0[j] = T[sc_ + j][d]; o1[j] = T[sc_ + 8 + j][d]; }
    unsigned short* dst = Vt + ((size_t)((n * NHEAD + h) * DHEAD + d)) * S_LEN + sb * 64 + sc_;
    *reinterpret_cast<ushort8v*>(dst)     = o0;
    *reinterpret_cast<ushort8v*>(dst + 8) = o1;
  } else {
    const int b3 = bid - 3584;
    const size_t base = (size_t)b3 * 1024 + (tid >> 6) * 256;
    const int l = tid & 63;
#pragma unroll
    for (int j = 0; j < 4; ++j) {
      const int v = Mg[base + j * 64 + l];
      u64 bj = __ballot(v != 0);
      if (l == 0) Mb[base / 64 + j] = bj;
    }
  }
}

// ---------------------------------------------------------------- attention
// LDS 48KB: per split sp: 3 bufs x (K 4KB @ +0, V 4KB @ +4096), region 24KB.
// Epilogue reuses bytes [0, 33792).
__global__ __launch_bounds__(512, 4) void attn_fwd(
    const unsigned short* __restrict__ Kb,   // bf16 [n][s][E]
    const unsigned short* __restrict__ Vtg,  // bf16 [n][h][d][s]
    const float* __restrict__ Qg,            // f32  [n][s][E]
    const u64* __restrict__ Mbit,            // [n][s][32]
    unsigned short* __restrict__ Og)         // bf16 [n][s][E]
{
  __shared__ __attribute__((aligned(16))) char SMEM[49152];

  const int bid = blockIdx.x;
  const int qb = bid & 15, h = (bid >> 4) & 15, n = bid >> 8;
  const int nh = n * NHEAD + h;
  const int tid = threadIdx.x;
  const int w = tid >> 6, sp = w >> 2, wq = w & 3;
  const int l = tid & 63, q5 = l & 31, hi = l >> 5;
  const int hi4 = hi * 4;
  const int q0w = qb * 128 + wq * 32;
  const int qg = q0w + q5;

  // Q fragments pre-scaled by log2e/32 (exp2 input comes straight from MFMA)
  FragU qf[4];
  {
    const float* qp = Qg + ((size_t)(n * S_LEN + qg)) * EMB + h * DHEAD + hi * 8;
#pragma unroll
    for (int s = 0; s < 4; ++s) {
      float4 a = *reinterpret_cast<const float4*>(qp + s * 16);
      float4 b = *reinterpret_cast<const float4*>(qp + s * 16 + 4);
      ushort8v u;
      u[0] = f2b(a.x * KSC); u[1] = f2b(a.y * KSC); u[2] = f2b(a.z * KSC); u[3] = f2b(a.w * KSC);
      u[4] = f2b(b.x * KSC); u[5] = f2b(b.y * KSC); u[6] = f2b(b.z * KSC); u[7] = f2b(b.w * KSC);
      qf[s].u = u;
    }
  }

  FragU ones;
#pragma unroll
  for (int j = 0; j < 8; ++j) ones.u[j] = 0x3F80;

  f32x16 acc0 = {}, acc1 = {}, racc = {};

  // staging (256 threads per split): K tile 32x128B, V tile 64x64B
  const int t8 = tid & 255;
  const int krow = t8 >> 3, kch = (t8 & 7) * 16;
  const char* kbase = (const char*)Kb +
      ((size_t)(n * S_LEN + sp * 1024 + krow)) * 2048 + h * 128 +
      (kch ^ ((krow & 7) << 4));
  const int vrow = t8 >> 2, vch = (t8 & 3) * 16;
  const char* vbase = (const char*)Vtg +
      ((size_t)(nh * DHEAD + vrow)) * 4096 + sp * 2048 +
      (vch ^ ((vrow & 3) << 4));

  char* Ksp = SMEM + sp * 24576;
  const int fsw  = (l & 7) << 4;   // K frag-read swizzle (128B rows)
  const int vfsw = (l & 3) << 4;   // V frag-read swizzle (64B rows)

  const unsigned* Mq32 = reinterpret_cast<const unsigned*>(
      Mbit + ((size_t)(n * S_LEN + qg)) * 32 + sp * 16);

#define ATTN_STAGE(BUF, IT) do {                                               \
    GLD16(kbase + (size_t)(IT) * 65536, Ksp + (BUF) * 8192 + t8 * 16);         \
    GLD16(vbase + (size_t)(IT) * 64,    Ksp + (BUF) * 8192 + 4096 + t8 * 16);  \
  } while (0)

#define ATTN_TILE(BUF, IT, WAITN, NBUF, DOSTAGE) do {                          \
    WAITVM(WAITN);                           /* tile IT's loads landed */      \
    __builtin_amdgcn_s_barrier();            /* publish to all waves   */      \
    asm volatile("" ::: "memory");                                             \
    if (DOSTAGE) ATTN_STAGE(NBUF, (IT) + 2); /* 2-deep prefetch        */      \
    const unsigned m32_ = Mq32[(IT)];                                          \
    f32x16 Sb = {};                                                            \
    __builtin_amdgcn_s_setprio(1);                                             \
    _Pragma("unroll") for (int s = 0; s < 4; ++s) {                            \
      FragU kf_;                                                               \
      kf_.u = *reinterpret_cast<const ushort8v*>(                              \
          Ksp + (BUF) * 8192 + (q5 * 128 + ((s * 32 + hi * 16) ^ fsw)));       \
      Sb = __builtin_amdgcn_mfma_f32_32x32x16_bf16(kf_.b, qf[s].b, Sb, 0, 0, 0); \
    }                                                                          \
    __builtin_amdgcn_s_setprio(0);                                             \
    float p_[16];                                                              \
    _Pragma("unroll") for (int t = 0; t < 4; ++t) {                            \
      const unsigned nib_ = m32_ >> (8 * t + hi4);                             \
      _Pragma("unroll") for (int e = 0; e < 4; ++e) {                          \
        const int r = 4 * t + e;                                               \
        float ex_ = __builtin_amdgcn_exp2f(Sb[r]);                             \
        const unsigned sm_ = (unsigned)((int)(nib_ << (31 - e)) >> 31);        \
        p_[r] = __uint_as_float(__float_as_uint(ex_) & sm_);                   \
      }                                                                        \
    }                                                                          \
    unsigned U0 = cvt_pk_bf16(p_[0],  p_[1]),  U1 = cvt_pk_bf16(p_[2],  p_[3]); \
    unsigned U2 = cvt_pk_bf16(p_[4],  p_[5]),  U3 = cvt_pk_bf16(p_[6],  p_[7]); \
    unsigned U4 = cvt_pk_bf16(p_[8],  p_[9]),  U5 = cvt_pk_bf16(p_[10], p_[11]); \
    unsigned U6 = cvt_pk_bf16(p_[12], p_[13]), U7 = cvt_pk_bf16(p_[14], p_[15]); \
    PSWAP(U0, U2); PSWAP(U1, U3); PSWAP(U4, U6); PSWAP(U5, U7);                \
    BFrag F0, F1;                                                              \
    F0.u32[0] = U0; F0.u32[1] = U1; F0.u32[2] = U2; F0.u32[3] = U3;            \
    F1.u32[0] = U4; F1.u32[1] = U5; F1.u32[2] = U6; F1.u32[3] = U7;            \
    __builtin_amdgcn_s_setprio(1);                                             \
    racc = __builtin_amdgcn_mfma_f32_32x32x16_bf16(ones.b, F0.b, racc, 0, 0, 0); \
    racc = __builtin_amdgcn_mfma_f32_32x32x16_bf16(ones.b, F1.b, racc, 0, 0, 0); \
    _Pragma("unroll") for (int db = 0; db < 2; ++db) {                         \
      FragU vf0_, vf1_;                                                        \
      vf0_.u = *reinterpret_cast<const ushort8v*>(                             \
          Ksp + (BUF) * 8192 + 4096 + ((db * 32 + q5) * 64 + ((0  + hi * 16) ^ vfsw))); \
      vf1_.u = *reinterpret_cast<const ushort8v*>(                             \
          Ksp + (BUF) * 8192 + 4096 + ((db * 32 + q5) * 64 + ((32 + hi * 16) ^ vfsw))); \
      if (db == 0) {                                                           \
        acc0 = __builtin_amdgcn_mfma_f32_32x32x16_bf16(vf0_.b, F0.b, acc0, 0, 0, 0); \
        acc0 = __builtin_amdgcn_mfma_f32_32x32x16_bf16(vf1_.b, F1.b, acc0, 0, 0, 0); \
      } else {                                                                 \
        acc1 = __builtin_amdgcn_mfma_f32_32x32x16_bf16(vf0_.b, F0.b, acc1, 0, 0, 0); \
        acc1 = __builtin_amdgcn_mfma_f32_32x32x16_bf16(vf1_.b, F1.b, acc1, 0, 0, 0); \
      }                                                                        \
    }                                                                          \
    __builtin_amdgcn_s_setprio(0);                                             \
  } while (0)

  ATTN_STAGE(0, 0);
  ATTN_STAGE(1, 1);
  for (int it = 0; it < 30; it += 3) {
    ATTN_TILE(0, it,     2, 2, 1);
    ATTN_TILE(1, it + 1, 2, 0, 1);
    ATTN_TILE(2, it + 2, 2, 1, 1);
  }
  ATTN_TILE(0, 30, 2, 0, 0);
  ATTN_TILE(1, 31, 0, 0, 0);

  // ---- combine splits + normalize + store ----
  const float rs = racc[0];   // ones-MFMA: every row holds the full kv-sum
  const int esw = (l & 7) << 4;

  __syncthreads();
  if (sp == 1) {
#pragma unroll
    for (int i = 0; i < 4; ++i) {
      f32x4 v0 = (f32x4){acc0[4*i], acc0[4*i+1], acc0[4*i+2], acc0[4*i+3]};
      f32x4 v1 = (f32x4){acc1[4*i], acc1[4*i+1], acc1[4*i+2], acc1[4*i+3]};
      *reinterpret_cast<f32x4*>(SMEM + wq * 8192 + l * 128 + ((i * 16) ^ esw))      = v0;
      *reinterpret_cast<f32x4*>(SMEM + wq * 8192 + l * 128 + ((64 + i * 16) ^ esw)) = v1;
    }
    *reinterpret_cast<float*>(SMEM + 32768 + wq * 256 + l * 4) = rs;
  }
  __syncthreads();
  if (sp == 0) {
    const float ors = *reinterpret_cast<const float*>(SMEM + 32768 + wq * 256 + l * 4);
    const float rin = 1.0f / (rs + ors);
    unsigned short* orow = Og + ((size_t)(n * S_LEN + qg)) * EMB + h * DHEAD + hi4;
#pragma unroll
    for (int db = 0; db < 2; ++db) {
#pragma unroll
      for (int t = 0; t < 4; ++t) {
        f32x4 pa = *reinterpret_cast<const f32x4*>(
            SMEM + wq * 8192 + l * 128 + ((db * 64 + t * 16) ^ esw));
        float a0, a1, a2, a3;
        if (db == 0) {
          a0 = (acc0[4*t]   + pa[0]) * rin; a1 = (acc0[4*t+1] + pa[1]) * rin;
          a2 = (acc0[4*t+2] + pa[2]) * rin; a3 = (acc0[4*t+3] + pa[3]) * rin;
        } else {
          a0 = (acc1[4*t]   + pa[0]) * rin; a1 = (acc1[4*t+1] + pa[1]) * rin;
          a2 = (acc1[4*t+2] + pa[2]) * rin; a3 = (acc1[4*t+3] + pa[3]) * rin;
        }
        uint2 pk;
        pk.x = cvt_pk_bf16(a0, a1);
        pk.y = cvt_pk_bf16(a2, a3);
        *reinterpret_cast<uint2*>(orow + db * 32 + t * 8) = pk;
      }
    }
  }
}

// ---------------------------------------------------------------- projection
// 128x128 tile, BK=64, 4 waves in 2x2, each wave 64x64 out (acc[4][4]).
__global__ __launch_bounds__(256, 2) void out_proj(
    const unsigned short* __restrict__ A,   // bf16 [4096][1024]
    const unsigned short* __restrict__ W,   // bf16 [1024][1024]
    const float* __restrict__ bias,
    float* __restrict__ Y)                  // f32 [4096][1024]
{
  __shared__ __attribute__((aligned(16))) char PSM[65536];  // A[2][16K] @0, B[2][16K] @32K

  const int bid = blockIdx.x;
  const int nb = bid & 7, mb = bid >> 3;   // mb 0..31, nb 0..7
  const int tid = threadIdx.x;
  const int w = tid >> 6, wr = w >> 1, wc = w & 1;
  const int l = tid & 63, lg = l >> 4, li = l & 15;
  const int m0 = mb * 128, n0 = nb * 128;

  f32x4 acc[4][4];
#pragma unroll
  for (int mi = 0; mi < 4; ++mi)
#pragma unroll
    for (int ci = 0; ci < 4; ++ci) acc[mi][ci] = (f32x4){0.f, 0.f, 0.f, 0.f};

  const int srow = tid >> 3;            // 0..31
  const int sch  = (tid & 7) * 16;
  const int ssw  = (srow & 7) << 4;
  const char* abase = (const char*)A + ((size_t)(m0 + srow)) * 2048 + (sch ^ ssw);
  const char* bbase = (const char*)W + ((size_t)(n0 + srow)) * 2048 + (sch ^ ssw);
  const int rsw = (li & 7) << 4;

  char* Asm = PSM;
  char* Bsm = PSM + 32768;

#define PROJ_STAGE(BUF, KK) do {                                               \
    _Pragma("unroll") for (int j = 0; j < 4; ++j) {                            \
      GLD16(abase + (size_t)j * 65536 + (KK) * 128,                            \
            Asm + (BUF) * 16384 + j * 4096 + tid * 16);                        \
      GLD16(bbase + (size_t)j * 65536 + (KK) * 128,                            \
            Bsm + (BUF) * 16384 + j * 4096 + tid * 16);                        \
    }                                                                          \
  } while (0)

#define PROJ_TILE(BUF, KK) do {                                                \
    __syncthreads();                                                           \
    if ((KK) + 1 < 16) PROJ_STAGE((BUF) ^ 1, (KK) + 1);                        \
    _Pragma("unroll") for (int s = 0; s < 2; ++s) {                            \
      FragU af_[4], bf_[4];                                                    \
      _Pragma("unroll") for (int mi = 0; mi < 4; ++mi)                         \
        af_[mi].u = *reinterpret_cast<const ushort8v*>(                        \
            Asm + (BUF) * 16384 +                                              \
            ((wr * 64 + mi * 16 + li) * 128 + ((s * 64 + lg * 16) ^ rsw)));    \
      _Pragma("unroll") for (int ci = 0; ci < 4; ++ci)                         \
        bf_[ci].u = *reinterpret_cast<const ushort8v*>(                        \
            Bsm + (BUF) * 16384 +                                              \
            ((wc * 64 + ci * 16 + li) * 128 + ((s * 64 + lg * 16) ^ rsw)));    \
      _Pragma("unroll") for (int mi = 0; mi < 4; ++mi)                         \
        _Pragma("unroll") for (int ci = 0; ci < 4; ++ci)                       \
          acc[mi][ci] = __builtin_amdgcn_mfma_f32_16x16x32_bf16(               \
              af_[mi].b, bf_[ci].b, acc[mi][ci], 0, 0, 0);                     \
    }                                                                          \
  } while (0)

  PROJ_STAGE(0, 0);
  for (int kk = 0; kk < 16; kk += 2) {
    PROJ_TILE(0, kk);
    PROJ_TILE(1, kk + 1);
  }

#pragma unroll
  for (int ci = 0; ci < 4; ++ci) {
    const int col = n0 + wc * 64 + ci * 16 + li;
    const float bv = bias[col];
#pragma unroll
    for (int mi = 0; mi < 4; ++mi) {
#pragma unroll
      for (int r = 0; r < 4; ++r) {
        const int row = m0 + wr * 64 + mi * 16 + lg * 4 + r;
        Y[(size_t)row * EMB + col] = acc[mi][ci][r] + bv;
      }
    }
  }
}

// ---------------------------------------------------------------- launch
extern "C" void kernel_launch(void* const* d_in, const int* in_sizes, int n_in,
                              void* d_out, int out_size, void* d_ws, size_t ws_size,
                              hipStream_t stream) {
  const float* Vg = (const float*)d_in[0];
  const float* Kg = (const float*)d_in[1];
  const float* Qg = (const float*)d_in[2];
  const int*   Mg = (const int*)d_in[3];
  const float* Wo = (const float*)d_in[4];
  const float* bo = (const float*)d_in[5];
  float* Y = (float*)d_out;

  char* ws = (char*)d_ws;
  unsigned short* Og   = (unsigned short*)(ws);                       //  8 MB
  unsigned short* Wb   = (unsigned short*)(ws + (8u << 20));          //  2 MB
  unsigned short* Kb16 = (unsigned short*)(ws + (10u << 20));         //  8 MB
  unsigned short* Vt   = (unsigned short*)(ws + (18u << 20));         //  8 MB
  u64*            Mbit = (u64*)(ws + (26u << 20));                    //  1 MB

  hipLaunchKernelGGL(prep, dim3(11776), dim3(256), 0, stream,
                     Wo, Wb, Kg, Kb16, Vg, Vt, Mg, Mbit);
  hipLaunchKernelGGL(attn_fwd, dim3(NBATCH * NHEAD * (S_LEN / 128)), dim3(512), 0, stream,
                     Kb16, Vt, Qg, Mbit, Og);
  hipLaunchKernelGGL(out_proj, dim3((NBATCH * S_LEN / 128) * (EMB / 128)), dim3(256), 0, stream,
                     Og, Wb, bo, Y);
}

// Round 16
// 87.053 us; speedup vs baseline: 1.0824x; 1.0824x over previous
//
#include <hip/hip_runtime.h>
#include <hip/hip_bf16.h>

// SelfAttention: N=2, S=2048, E=1024, H=16, D=64.
// Round 16 = round 14 (best, 87.5us) reverted verbatim after r15's counted-
// vmcnt pipeline lost to bank conflicts (64B V rows -> 8-way).
// attn: 32x32x16 MFMA, KV-split 8-wave, KVBLK=64 (128B rows, 3-bit XOR
// swizzle), pre-scaled Q, ones-MFMA rowsum, sign-AND masking, cvt_pk +
// permlane32_swap in-register P, gload_lds dbuf staging, setprio clusters.
// out_proj: 128x128xBK64. prep: fused convert/transpose/bitmap.

#define S_LEN  2048
#define EMB    1024
#define NHEAD  16
#define DHEAD  64
#define NBATCH 2

// log2(e)/32: folded into Q so QK^T lands pre-scaled for exp2
#define KSC 0.04508422002778011f

typedef float              f32x4    __attribute__((ext_vector_type(4)));
typedef float              f32x16   __attribute__((ext_vector_type(16)));
typedef __bf16             bf16x8   __attribute__((ext_vector_type(8)));
typedef unsigned short     ushort8v __attribute__((ext_vector_type(8)));
typedef unsigned long long u64;

union FragU { ushort8v u; bf16x8 b; };
union BFrag { unsigned u32[4]; bf16x8 b; };

__device__ __forceinline__ unsigned short f2b(float f) {
  union { __hip_bfloat16 h; unsigned short u; } c;
  c.h = __float2bfloat16(f);
  return c.u;
}

__device__ __forceinline__ unsigned int cvt_pk_bf16(float lo, float hi) {
  unsigned int r;
  asm("v_cvt_pk_bf16_f32 %0, %1, %2" : "=v"(r) : "v"(lo), "v"(hi));
  return r;
}

#define PSWAP(a, b) asm("v_permlane32_swap_b32 %0, %1" : "+v"(a), "+v"(b))

#define GLD16(g, l)                                                            \
  __builtin_amdgcn_global_load_lds(                                            \
      (__attribute__((address_space(1))) void*)(g),                            \
      (__attribute__((address_space(3))) void*)(l), 16, 0, 0)

// ------------------------------------------------------- fused prep kernel
__global__ __launch_bounds__(256) void prep(
    const float* __restrict__ Wo, unsigned short* __restrict__ Wb,
    const float* __restrict__ Kg, unsigned short* __restrict__ Kb,
    const float* __restrict__ Vg, unsigned short* __restrict__ Vt,
    const int* __restrict__ Mg,   u64* __restrict__ Mb)
{
  const int bid = blockIdx.x;
  const int tid = threadIdx.x;
  if (bid < 2560) {
    const float* X = (bid < 512) ? Wo : Kg;
    unsigned short* Y = (bid < 512) ? Wb : Kb;
    const int bb = (bid < 512) ? bid : bid - 512;
    const size_t i = ((size_t)bb * 256 + tid) * 8;
    float4 a = *reinterpret_cast<const float4*>(X + i);
    float4 b = *reinterpret_cast<const float4*>(X + i + 4);
    ushort8v u;
    u[0] = f2b(a.x); u[1] = f2b(a.y); u[2] = f2b(a.z); u[3] = f2b(a.w);
    u[4] = f2b(b.x); u[5] = f2b(b.y); u[6] = f2b(b.z); u[7] = f2b(b.w);
    *reinterpret_cast<ushort8v*>(Y + i) = u;
  } else if (bid < 3584) {
    __shared__ unsigned short T[64][72];
    const int b2 = bid - 2560;
    const int sb = b2 & 31, h = (b2 >> 5) & 15, n = b2 >> 9;
    const int r = tid >> 2, cb = (tid & 3) * 16;
    const float* src = Vg + ((size_t)(n * S_LEN + sb * 64 + r)) * EMB + h * DHEAD + cb;
    ushort8v u0, u1;
#pragma unroll
    for (int j = 0; j < 2; ++j) {
      float4 x = *reinterpret_cast<const float4*>(src + j * 4);
      u0[j*4+0] = f2b(x.x); u0[j*4+1] = f2b(x.y); u0[j*4+2] = f2b(x.z); u0[j*4+3] = f2b(x.w);
      float4 y = *reinterpret_cast<const float4*>(src + 8 + j * 4);
      u1[j*4+0] = f2b(y.x); u1[j*4+1] = f2b(y.y); u1[j*4+2] = f2b(y.z); u1[j*4+3] = f2b(y.w);
    }
    *reinterpret_cast<ushort8v*>(&T[r][cb])     = u0;
    *reinterpret_cast<ushort8v*>(&T[r][cb + 8]) = u1;
    __syncthreads();
    const int d = tid >> 2, sc_ = (tid & 3) * 16;
    ushort8v o0, o1;
#pragma unroll
    for (int j = 0; j < 8; ++j) { o0[j] = T[sc_ + j][d]; o1[j] = T[sc_ + 8 + j][d]; }
    unsigned short* dst = Vt + ((size_t)((n * NHEAD + h) * DHEAD + d)) * S_LEN + sb * 64 + sc_;
    *reinterpret_cast<ushort8v*>(dst)     = o0;
    *reinterpret_cast<ushort8v*>(dst + 8) = o1;
  } else {
    const int b3 = bid - 3584;
    const size_t base = (size_t)b3 * 1024 + (tid >> 6) * 256;
    const int l = tid & 63;
#pragma unroll
    for (int j = 0; j < 4; ++j) {
      const int v = Mg[base + j * 64 + l];
      u64 bj = __ballot(v != 0);
      if (l == 0) Mb[base / 64 + j] = bj;
    }
  }
}

// ---------------------------------------------------------------- attention
__global__ __launch_bounds__(512, 4) void attn_fwd(
    const unsigned short* __restrict__ Kb,   // bf16 [n][s][E]
    const unsigned short* __restrict__ Vtg,  // bf16 [n][h][d][s]
    const float* __restrict__ Qg,            // f32  [n][s][E]
    const u64* __restrict__ Mbit,            // [n][s][32]
    unsigned short* __restrict__ Og)         // bf16 [n][s][E]
{
  __shared__ __attribute__((aligned(16))) char SMEM[65536];

  const int bid = blockIdx.x;
  const int qb = bid & 15, h = (bid >> 4) & 15, n = bid >> 8;
  const int nh = n * NHEAD + h;
  const int tid = threadIdx.x;
  const int w = tid >> 6, sp = w >> 2, wq = w & 3;
  const int l = tid & 63, q5 = l & 31, hi = l >> 5;
  const int hi4 = hi * 4;
  const int q0w = qb * 128 + wq * 32;
  const int qg = q0w + q5;

  // Q fragments pre-scaled by log2e/32 (exp2 input comes straight from MFMA)
  FragU qf[4];
  {
    const float* qp = Qg + ((size_t)(n * S_LEN + qg)) * EMB + h * DHEAD + hi * 8;
#pragma unroll
    for (int s = 0; s < 4; ++s) {
      float4 a = *reinterpret_cast<const float4*>(qp + s * 16);
      float4 b = *reinterpret_cast<const float4*>(qp + s * 16 + 4);
      ushort8v u;
      u[0] = f2b(a.x * KSC); u[1] = f2b(a.y * KSC); u[2] = f2b(a.z * KSC); u[3] = f2b(a.w * KSC);
      u[4] = f2b(b.x * KSC); u[5] = f2b(b.y * KSC); u[6] = f2b(b.z * KSC); u[7] = f2b(b.w * KSC);
      qf[s].u = u;
    }
  }

  FragU ones;
#pragma unroll
  for (int j = 0; j < 8; ++j) ones.u[j] = 0x3F80;

  f32x16 acc0 = {}, acc1 = {}, racc = {};

  const int t8 = tid & 255;
  const int srow = t8 >> 3, sc = t8 & 7;
  const char* kbase = (const char*)Kb +
      ((size_t)(n * S_LEN + sp * 1024 + srow)) * 2048 + h * 128 +
      ((sc * 16) ^ ((srow & 7) << 4));
  const char* vbase = (const char*)Vtg +
      ((size_t)(nh * DHEAD + srow)) * 4096 + sp * 2048 +
      ((sc * 16) ^ ((srow & 7) << 4));

  char* Ksp = SMEM + sp * 16384;
  char* Vsp = SMEM + 32768 + sp * 16384;
  const int fsw = (l & 7) << 4;

  const u64* Mq = Mbit + ((size_t)(n * S_LEN + qg)) * 32 + sp * 16;
  u64 mq_cur = Mq[0];

#define ATTN_STAGE(BUF, IT) do {                                               \
    GLD16(kbase + (size_t)(IT) * 131072,          Ksp + (BUF) * 8192 + t8 * 16); \
    GLD16(kbase + (size_t)(IT) * 131072 + 65536,  Ksp + (BUF) * 8192 + 4096 + t8 * 16); \
    GLD16(vbase + (size_t)(IT) * 128,             Vsp + (BUF) * 8192 + t8 * 16); \
    GLD16(vbase + (size_t)(IT) * 128 + 131072,    Vsp + (BUF) * 8192 + 4096 + t8 * 16); \
  } while (0)

#define ATTN_TILE(BUF, IT) do {                                                \
    __syncthreads();                                                           \
    if ((IT) + 1 < 16) ATTN_STAGE((BUF) ^ 1, (IT) + 1);                        \
    const u64 mrow_ = mq_cur;                                                  \
    if ((IT) + 1 < 16) mq_cur = Mq[(IT) + 1];                                  \
    _Pragma("unroll") for (int b = 0; b < 2; ++b) {                            \
      f32x16 Sb = {};                                                          \
      __builtin_amdgcn_s_setprio(1);                                           \
      _Pragma("unroll") for (int s = 0; s < 4; ++s) {                          \
        FragU kf_;                                                             \
        kf_.u = *reinterpret_cast<const ushort8v*>(                            \
            Ksp + (BUF) * 8192 + ((b * 32 + q5) * 128 + ((s * 32 + hi * 16) ^ fsw))); \
        Sb = __builtin_amdgcn_mfma_f32_32x32x16_bf16(kf_.b, qf[s].b, Sb, 0, 0, 0); \
      }                                                                        \
      __builtin_amdgcn_s_setprio(0);                                           \
      const unsigned m32_ = b ? (unsigned)(mrow_ >> 32) : (unsigned)mrow_;     \
      float p_[16];                                                            \
      _Pragma("unroll") for (int t = 0; t < 4; ++t) {                          \
        const unsigned nib_ = m32_ >> (8 * t + hi4);                           \
        _Pragma("unroll") for (int e = 0; e < 4; ++e) {                        \
          const int r = 4 * t + e;                                             \
          float ex_ = __builtin_amdgcn_exp2f(Sb[r]);                           \
          const unsigned sm_ = (unsigned)((int)(nib_ << (31 - e)) >> 31);      \
          p_[r] = __uint_as_float(__float_as_uint(ex_) & sm_);                 \
        }                                                                      \
      }                                                                        \
      unsigned U0 = cvt_pk_bf16(p_[0],  p_[1]),  U1 = cvt_pk_bf16(p_[2],  p_[3]); \
      unsigned U2 = cvt_pk_bf16(p_[4],  p_[5]),  U3 = cvt_pk_bf16(p_[6],  p_[7]); \
      unsigned U4 = cvt_pk_bf16(p_[8],  p_[9]),  U5 = cvt_pk_bf16(p_[10], p_[11]); \
      unsigned U6 = cvt_pk_bf16(p_[12], p_[13]), U7 = cvt_pk_bf16(p_[14], p_[15]); \
      PSWAP(U0, U2); PSWAP(U1, U3); PSWAP(U4, U6); PSWAP(U5, U7);              \
      BFrag F0, F1;                                                            \
      F0.u32[0] = U0; F0.u32[1] = U1; F0.u32[2] = U2; F0.u32[3] = U3;          \
      F1.u32[0] = U4; F1.u32[1] = U5; F1.u32[2] = U6; F1.u32[3] = U7;          \
      __builtin_amdgcn_s_setprio(1);                                           \
      racc = __builtin_amdgcn_mfma_f32_32x32x16_bf16(ones.b, F0.b, racc, 0, 0, 0); \
      racc = __builtin_amdgcn_mfma_f32_32x32x16_bf16(ones.b, F1.b, racc, 0, 0, 0); \
      _Pragma("unroll") for (int db = 0; db < 2; ++db) {                       \
        FragU vf0_, vf1_;                                                      \
        vf0_.u = *reinterpret_cast<const ushort8v*>(                           \
            Vsp + (BUF) * 8192 + ((db * 32 + q5) * 128 + (((2 * b) * 32 + hi * 16) ^ fsw))); \
        vf1_.u = *reinterpret_cast<const ushort8v*>(                           \
            Vsp + (BUF) * 8192 + ((db * 32 + q5) * 128 + (((2 * b + 1) * 32 + hi * 16) ^ fsw))); \
        if (db == 0) {                                                         \
          acc0 = __builtin_amdgcn_mfma_f32_32x32x16_bf16(vf0_.b, F0.b, acc0, 0, 0, 0); \
          acc0 = __builtin_amdgcn_mfma_f32_32x32x16_bf16(vf1_.b, F1.b, acc0, 0, 0, 0); \
        } else {                                                               \
          acc1 = __builtin_amdgcn_mfma_f32_32x32x16_bf16(vf0_.b, F0.b, acc1, 0, 0, 0); \
          acc1 = __builtin_amdgcn_mfma_f32_32x32x16_bf16(vf1_.b, F1.b, acc1, 0, 0, 0); \
        }                                                                      \
      }                                                                        \
      __builtin_amdgcn_s_setprio(0);                                           \
    }                                                                          \
  } while (0)

  ATTN_STAGE(0, 0);
  for (int it = 0; it < 16; it += 2) {
    ATTN_TILE(0, it);
    ATTN_TILE(1, it + 1);
  }

  // ---- combine splits + normalize + store ----
  const float rs = racc[0];   // ones-MFMA: every row holds the full kv-sum
  const int esw = (l & 7) << 4;

  __syncthreads();
  if (sp == 1) {
#pragma unroll
    for (int i = 0; i < 4; ++i) {
      f32x4 v0 = (f32x4){acc0[4*i], acc0[4*i+1], acc0[4*i+2], acc0[4*i+3]};
      f32x4 v1 = (f32x4){acc1[4*i], acc1[4*i+1], acc1[4*i+2], acc1[4*i+3]};
      *reinterpret_cast<f32x4*>(SMEM + wq * 8192 + l * 128 + ((i * 16) ^ esw))      = v0;
      *reinterpret_cast<f32x4*>(SMEM + wq * 8192 + l * 128 + ((64 + i * 16) ^ esw)) = v1;
    }
    *reinterpret_cast<float*>(SMEM + 32768 + wq * 256 + l * 4) = rs;
  }
  __syncthreads();
  if (sp == 0) {
    const float ors = *reinterpret_cast<const float*>(SMEM + 32768 + wq * 256 + l * 4);
    const float rin = 1.0f / (rs + ors);
    unsigned short* orow = Og + ((size_t)(n * S_LEN + qg)) * EMB + h * DHEAD + hi4;
#pragma unroll
    for (int db = 0; db < 2; ++db) {
#pragma unroll
      for (int t = 0; t < 4; ++t) {
        f32x4 pa = *reinterpret_cast<const f32x4*>(
            SMEM + wq * 8192 + l * 128 + ((db * 64 + t * 16) ^ esw));
        float a0, a1, a2, a3;
        if (db == 0) {
          a0 = (acc0[4*t]   + pa[0]) * rin; a1 = (acc0[4*t+1] + pa[1]) * rin;
          a2 = (acc0[4*t+2] + pa[2]) * rin; a3 = (acc0[4*t+3] + pa[3]) * rin;
        } else {
          a0 = (acc1[4*t]   + pa[0]) * rin; a1 = (acc1[4*t+1] + pa[1]) * rin;
          a2 = (acc1[4*t+2] + pa[2]) * rin; a3 = (acc1[4*t+3] + pa[3]) * rin;
        }
        uint2 pk;
        pk.x = cvt_pk_bf16(a0, a1);
        pk.y = cvt_pk_bf16(a2, a3);
        *reinterpret_cast<uint2*>(orow + db * 32 + t * 8) = pk;
      }
    }
  }
}

// ---------------------------------------------------------------- projection
// 128x128 tile, BK=64, 4 waves in 2x2, each wave 64x64 out (acc[4][4]).
__global__ __launch_bounds__(256, 2) void out_proj(
    const unsigned short* __restrict__ A,   // bf16 [4096][1024]
    const unsigned short* __restrict__ W,   // bf16 [1024][1024]
    const float* __restrict__ bias,
    float* __restrict__ Y)                  // f32 [4096][1024]
{
  __shared__ __attribute__((aligned(16))) char PSM[65536];  // A[2][16K] @0, B[2][16K] @32K

  const int bid = blockIdx.x;
  const int nb = bid & 7, mb = bid >> 3;   // mb 0..31, nb 0..7
  const int tid = threadIdx.x;
  const int w = tid >> 6, wr = w >> 1, wc = w & 1;
  const int l = tid & 63, lg = l >> 4, li = l & 15;
  const int m0 = mb * 128, n0 = nb * 128;

  f32x4 acc[4][4];
#pragma unroll
  for (int mi = 0; mi < 4; ++mi)
#pragma unroll
    for (int ci = 0; ci < 4; ++ci) acc[mi][ci] = (f32x4){0.f, 0.f, 0.f, 0.f};

  const int srow = tid >> 3;            // 0..31
  const int sch  = (tid & 7) * 16;
  const int ssw  = (srow & 7) << 4;
  const char* abase = (const char*)A + ((size_t)(m0 + srow)) * 2048 + (sch ^ ssw);
  const char* bbase = (const char*)W + ((size_t)(n0 + srow)) * 2048 + (sch ^ ssw);
  const int rsw = (li & 7) << 4;

  char* Asm = PSM;
  char* Bsm = PSM + 32768;

#define PROJ_STAGE(BUF, KK) do {                                               \
    _Pragma("unroll") for (int j = 0; j < 4; ++j) {                            \
      GLD16(abase + (size_t)j * 65536 + (KK) * 128,                            \
            Asm + (BUF) * 16384 + j * 4096 + tid * 16);                        \
      GLD16(bbase + (size_t)j * 65536 + (KK) * 128,                            \
            Bsm + (BUF) * 16384 + j * 4096 + tid * 16);                        \
    }                                                                          \
  } while (0)

#define PROJ_TILE(BUF, KK) do {                                                \
    __syncthreads();                                                           \
    if ((KK) + 1 < 16) PROJ_STAGE((BUF) ^ 1, (KK) + 1);                        \
    _Pragma("unroll") for (int s = 0; s < 2; ++s) {                            \
      FragU af_[4], bf_[4];                                                    \
      _Pragma("unroll") for (int mi = 0; mi < 4; ++mi)                         \
        af_[mi].u = *reinterpret_cast<const ushort8v*>(                        \
            Asm + (BUF) * 16384 +                                              \
            ((wr * 64 + mi * 16 + li) * 128 + ((s * 64 + lg * 16) ^ rsw)));    \
      _Pragma("unroll") for (int ci = 0; ci < 4; ++ci)                         \
        bf_[ci].u = *reinterpret_cast<const ushort8v*>(                        \
            Bsm + (BUF) * 16384 +                                              \
            ((wc * 64 + ci * 16 + li) * 128 + ((s * 64 + lg * 16) ^ rsw)));    \
      _Pragma("unroll") for (int mi = 0; mi < 4; ++mi)                         \
        _Pragma("unroll") for (int ci = 0; ci < 4; ++ci)                       \
          acc[mi][ci] = __builtin_amdgcn_mfma_f32_16x16x32_bf16(               \
              af_[mi].b, bf_[ci].b, acc[mi][ci], 0, 0, 0);                     \
    }                                                                          \
  } while (0)

  PROJ_STAGE(0, 0);
  for (int kk = 0; kk < 16; kk += 2) {
    PROJ_TILE(0, kk);
    PROJ_TILE(1, kk + 1);
  }

#pragma unroll
  for (int ci = 0; ci < 4; ++ci) {
    const int col = n0 + wc * 64 + ci * 16 + li;
    const float bv = bias[col];
#pragma unroll
    for (int mi = 0; mi < 4; ++mi) {
#pragma unroll
      for (int r = 0; r < 4; ++r) {
        const int row = m0 + wr * 64 + mi * 16 + lg * 4 + r;
        Y[(size_t)row * EMB + col] = acc[mi][ci][r] + bv;
      }
    }
  }
}

// ---------------------------------------------------------------- launch
extern "C" void kernel_launch(void* const* d_in, const int* in_sizes, int n_in,
                              void* d_out, int out_size, void* d_ws, size_t ws_size,
                              hipStream_t stream) {
  const float* Vg = (const float*)d_in[0];
  const float* Kg = (const float*)d_in[1];
  const float* Qg = (const float*)d_in[2];
  const int*   Mg = (const int*)d_in[3];
  const float* Wo = (const float*)d_in[4];
  const float* bo = (const float*)d_in[5];
  float* Y = (float*)d_out;

  char* ws = (char*)d_ws;
  unsigned short* Og   = (unsigned short*)(ws);                       //  8 MB
  unsigned short* Wb   = (unsigned short*)(ws + (8u << 20));          //  2 MB
  unsigned short* Kb16 = (unsigned short*)(ws + (10u << 20));         //  8 MB
  unsigned short* Vt   = (unsigned short*)(ws + (18u << 20));         //  8 MB
  u64*            Mbit = (u64*)(ws + (26u << 20));                    //  1 MB

  hipLaunchKernelGGL(prep, dim3(11776), dim3(256), 0, stream,
                     Wo, Wb, Kg, Kb16, Vg, Vt, Mg, Mbit);
  hipLaunchKernelGGL(attn_fwd, dim3(NBATCH * NHEAD * (S_LEN / 128)), dim3(512), 0, stream,
                     Kb16, Vt, Qg, Mbit, Og);
  hipLaunchKernelGGL(out_proj, dim3((NBATCH * S_LEN / 128) * (EMB / 128)), dim3(256), 0, stream,
                     Og, Wb, bo, Y);
}